// Round 1
// baseline (208.667 us; speedup 1.0000x reference)
//
#include <hip/hip_runtime.h>

#define BATCH 4
#define CH    256
#define SVOL  32768   // 32*32*32
#define SV4   8192    // SVOL/4
#define NC    4       // channel chunks
#define CCH   64      // channels per chunk

// ws layout (floats):
//   [0, 1024)                      coef[b][c]
//   [1024, 1024+NC*BATCH*SVOL)     partial[chunk][b][s]   (2 MB)
//   [.., +BATCH*SVOL)              small[b][s]            (512 KB)

__global__ void __launch_bounds__(256)
coef_kernel(const float* __restrict__ istyle,
            const float* __restrict__ W_style,
            const float* __restrict__ b_style,
            const float* __restrict__ wk,
            float* __restrict__ coef) {
    int tid  = threadIdx.x;
    int wave = blockIdx.x * 4 + (tid >> 6);   // 0..1023
    int lane = tid & 63;
    int b = wave >> 8;
    int c = wave & 255;
    const float* is = istyle + b * 512;
    const float* wr = W_style + c * 512;
    float acc = 0.f;
    #pragma unroll
    for (int j = 0; j < 8; ++j) {
        int k = lane + j * 64;
        acc += is[k] * wr[k];
    }
    #pragma unroll
    for (int off = 32; off >= 1; off >>= 1)
        acc += __shfl_down(acc, off, 64);
    if (lane == 0)
        coef[b * 256 + c] = wk[c] * (acc + b_style[c] + 1.0f);
}

__global__ void __launch_bounds__(256)
reduce_c_kernel(const float4* __restrict__ x4,
                const float* __restrict__ coef,
                float4* __restrict__ partial4) {
    __shared__ float cf[CCH];
    int chunk = blockIdx.y;
    int g  = blockIdx.x * 256 + threadIdx.x;  // 0..BATCH*SV4-1
    int b  = g >> 13;                         // / SV4
    int s4 = g & (SV4 - 1);
    if (threadIdx.x < CCH)
        cf[threadIdx.x] = coef[b * 256 + chunk * CCH + threadIdx.x];
    __syncthreads();
    const float4* xp = x4 + (size_t)(b * CH + chunk * CCH) * SV4 + s4;
    float4 acc = {0.f, 0.f, 0.f, 0.f};
    #pragma unroll 16
    for (int cc = 0; cc < CCH; ++cc) {
        float4 v = xp[(size_t)cc * SV4];
        float w = cf[cc];
        acc.x += v.x * w; acc.y += v.y * w;
        acc.z += v.z * w; acc.w += v.w * w;
    }
    partial4[(size_t)(chunk * BATCH + b) * SV4 + s4] = acc;
}

__global__ void __launch_bounds__(256)
finalize_small_kernel(const float4* __restrict__ partial4,
                      const float4* __restrict__ prev4,
                      float4* __restrict__ small4) {
    int g  = blockIdx.x * 256 + threadIdx.x;  // 0..BATCH*SV4-1
    int b  = g >> 13;
    int s4 = g & (SV4 - 1);
    float4 acc = prev4[g];
    #pragma unroll
    for (int chunk = 0; chunk < NC; ++chunk) {
        float4 p = partial4[(size_t)(chunk * BATCH + b) * SV4 + s4];
        acc.x += p.x; acc.y += p.y; acc.z += p.z; acc.w += p.w;
    }
    small4[g] = acc;
}

// Fused 2x trilinear upsample + [1,2,1]^3/64 blur, expressed as a 3-tap
// separable stencil on the SMALL grid. For output index o (j=o>>1):
//   even o=2j : (5,10,1)/16 over a[j-1], a[j], a[j+1]   (edge-clamped)
//   odd  o=2j+1:(1,10,5)/16
// Product over 3 axes, final scale 1/4096.
__global__ void __launch_bounds__(256)
upblur_kernel(const float* __restrict__ small,
              float* __restrict__ out) {
    int g  = blockIdx.x * 256 + threadIdx.x;  // 0..BATCH*64^3-1
    int xo = g & 63;
    int yo = (g >> 6) & 63;
    int zo = (g >> 12) & 63;
    int b  = g >> 18;

    int jx = xo >> 1, jy = yo >> 1, jz = zo >> 1;
    int px = xo & 1,  py = yo & 1,  pz = zo & 1;

    int xi[3] = { jx > 0 ? jx - 1 : 0, jx, jx < 31 ? jx + 1 : 31 };
    int yi[3] = { jy > 0 ? jy - 1 : 0, jy, jy < 31 ? jy + 1 : 31 };
    int zi[3] = { jz > 0 ? jz - 1 : 0, jz, jz < 31 ? jz + 1 : 31 };

    float wx[3] = { px ? 1.f : 5.f, 10.f, px ? 5.f : 1.f };
    float wy[3] = { py ? 1.f : 5.f, 10.f, py ? 5.f : 1.f };
    float wz[3] = { pz ? 1.f : 5.f, 10.f, pz ? 5.f : 1.f };

    const float* base = small + (size_t)b * SVOL;
    float acc = 0.f;
    #pragma unroll
    for (int a = 0; a < 3; ++a) {
        const float* pzrow = base + zi[a] * 1024;
        float accy = 0.f;
        #pragma unroll
        for (int c = 0; c < 3; ++c) {
            const float* pyrow = pzrow + yi[c] * 32;
            float row = wx[0] * pyrow[xi[0]] + wx[1] * pyrow[xi[1]] + wx[2] * pyrow[xi[2]];
            accy += wy[c] * row;
        }
        acc += wz[a] * accy;
    }
    out[g] = acc * (1.0f / 4096.0f);
}

extern "C" void kernel_launch(void* const* d_in, const int* in_sizes, int n_in,
                              void* d_out, int out_size, void* d_ws, size_t ws_size,
                              hipStream_t stream) {
    const float* x       = (const float*)d_in[0];
    const float* prev    = (const float*)d_in[1];
    const float* istyle  = (const float*)d_in[2];
    const float* W_style = (const float*)d_in[3];
    const float* b_style = (const float*)d_in[4];
    const float* wk      = (const float*)d_in[5];  // conv_weight flat = (C,)
    float* ws      = (float*)d_ws;
    float* coef    = ws;                               // 1024 floats
    float* partial = ws + 1024;                        // NC*BATCH*SVOL floats
    float* small   = partial + (size_t)NC * BATCH * SVOL;

    coef_kernel<<<256, 256, 0, stream>>>(istyle, W_style, b_style, wk, coef);

    dim3 g2(BATCH * SV4 / 256, NC);   // (128, 4)
    reduce_c_kernel<<<g2, 256, 0, stream>>>((const float4*)x, coef, (float4*)partial);

    finalize_small_kernel<<<BATCH * SV4 / 256, 256, 0, stream>>>(
        (const float4*)partial, (const float4*)prev, (float4*)small);

    upblur_kernel<<<BATCH * 64 * 64 * 64 / 256, 256, 0, stream>>>(small, (float*)d_out);
}

// Round 3
// 195.950 us; speedup vs baseline: 1.0649x; 1.0649x over previous
//
#include <hip/hip_runtime.h>

#define BATCH 4
#define CH    256
#define SVOL  32768   // 32*32*32
#define SV4   8192    // SVOL/4
#define TILE  32      // spatial float4 positions per block
#define NCH   8       // channel chunks per block
#define CCH   32      // channels per chunk

typedef float floatx4 __attribute__((ext_vector_type(4)));

// ws layout (floats):
//   [0, 1024)          coef[b][c]
//   [1024, +BATCH*SVOL) small[b][s]   (512 KB)

__global__ void __launch_bounds__(256)
coef_kernel(const float* __restrict__ istyle,
            const float* __restrict__ W_style,
            const float* __restrict__ b_style,
            const float* __restrict__ wk,
            float* __restrict__ coef) {
    int tid  = threadIdx.x;
    int wave = blockIdx.x * 4 + (tid >> 6);   // 0..1023
    int lane = tid & 63;
    int b = wave >> 8;
    int c = wave & 255;
    const float* is = istyle + b * 512;
    const float* wr = W_style + c * 512;
    float acc = 0.f;
    #pragma unroll
    for (int j = 0; j < 8; ++j) {
        int k = lane + j * 64;
        acc += is[k] * wr[k];
    }
    #pragma unroll
    for (int off = 32; off >= 1; off >>= 1)
        acc += __shfl_down(acc, off, 64);
    if (lane == 0)
        coef[b * 256 + c] = wk[c] * (acc + b_style[c] + 1.0f);
}

// One block: TILE spatial float4 positions x all 256 channels.
// thread t: position = t & 31, chunk = t >> 5 (32 channels each).
// LDS-reduce the 8 chunks, add prev, write small. No partial round-trip.
__global__ void __launch_bounds__(256)
reduce_c_kernel(const floatx4* __restrict__ x4,
                const float* __restrict__ coef,
                const floatx4* __restrict__ prev4,
                floatx4* __restrict__ small4) {
    __shared__ float   cf[CH];
    __shared__ floatx4 red[NCH][TILE];

    int t     = threadIdx.x;
    int pos   = t & (TILE - 1);
    int chunk = t >> 5;
    int gpos  = blockIdx.x * TILE + pos;      // 0..BATCH*SV4-1
    int b     = gpos >> 13;                   // / SV4
    int s4    = gpos & (SV4 - 1);

    cf[t] = coef[b * CH + t];                 // all 256 coef for this b
    __syncthreads();

    const floatx4* xp = x4 + (size_t)(b * CH + chunk * CCH) * SV4 + s4;
    floatx4 acc = {0.f, 0.f, 0.f, 0.f};
    #pragma unroll 16
    for (int cc = 0; cc < CCH; ++cc) {
        floatx4 v = __builtin_nontemporal_load(&xp[(size_t)cc * SV4]);
        float   w = cf[chunk * CCH + cc];
        acc += v * w;
    }
    red[chunk][pos] = acc;
    __syncthreads();

    if (t < TILE) {
        floatx4 r = prev4[gpos];
        #pragma unroll
        for (int k = 0; k < NCH; ++k)
            r += red[k][t];
        small4[gpos] = r;
    }
}

// Fused 2x trilinear upsample + [1,2,1]^3/64 blur as a 3-tap separable
// stencil on the SMALL grid: even o=2j -> (5,10,1)/16, odd -> (1,10,5)/16,
// edge-clamped; product over axes, final scale 1/4096.
__global__ void __launch_bounds__(256)
upblur_kernel(const float* __restrict__ small,
              float* __restrict__ out) {
    int g  = blockIdx.x * 256 + threadIdx.x;  // 0..BATCH*64^3-1
    int xo = g & 63;
    int yo = (g >> 6) & 63;
    int zo = (g >> 12) & 63;
    int b  = g >> 18;

    int jx = xo >> 1, jy = yo >> 1, jz = zo >> 1;
    int px = xo & 1,  py = yo & 1,  pz = zo & 1;

    int xi[3] = { jx > 0 ? jx - 1 : 0, jx, jx < 31 ? jx + 1 : 31 };
    int yi[3] = { jy > 0 ? jy - 1 : 0, jy, jy < 31 ? jy + 1 : 31 };
    int zi[3] = { jz > 0 ? jz - 1 : 0, jz, jz < 31 ? jz + 1 : 31 };

    float wx[3] = { px ? 1.f : 5.f, 10.f, px ? 5.f : 1.f };
    float wy[3] = { py ? 1.f : 5.f, 10.f, py ? 5.f : 1.f };
    float wz[3] = { pz ? 1.f : 5.f, 10.f, pz ? 5.f : 1.f };

    const float* base = small + (size_t)b * SVOL;
    float acc = 0.f;
    #pragma unroll
    for (int a = 0; a < 3; ++a) {
        const float* pzrow = base + zi[a] * 1024;
        float accy = 0.f;
        #pragma unroll
        for (int c = 0; c < 3; ++c) {
            const float* pyrow = pzrow + yi[c] * 32;
            float row = wx[0] * pyrow[xi[0]] + wx[1] * pyrow[xi[1]] + wx[2] * pyrow[xi[2]];
            accy += wy[c] * row;
        }
        acc += wz[a] * accy;
    }
    out[g] = acc * (1.0f / 4096.0f);
}

extern "C" void kernel_launch(void* const* d_in, const int* in_sizes, int n_in,
                              void* d_out, int out_size, void* d_ws, size_t ws_size,
                              hipStream_t stream) {
    const float* x       = (const float*)d_in[0];
    const float* prev    = (const float*)d_in[1];
    const float* istyle  = (const float*)d_in[2];
    const float* W_style = (const float*)d_in[3];
    const float* b_style = (const float*)d_in[4];
    const float* wk      = (const float*)d_in[5];  // conv_weight flat = (C,)
    float* ws    = (float*)d_ws;
    float* coef  = ws;          // 1024 floats
    float* small = ws + 1024;   // BATCH*SVOL floats

    coef_kernel<<<256, 256, 0, stream>>>(istyle, W_style, b_style, wk, coef);

    reduce_c_kernel<<<BATCH * SV4 / TILE, 256, 0, stream>>>(
        (const floatx4*)x, coef, (const floatx4*)prev, (floatx4*)small);

    upblur_kernel<<<BATCH * 64 * 64 * 64 / 256, 256, 0, stream>>>(small, (float*)d_out);
}